// Round 1
// baseline (12315.231 us; speedup 1.0000x reference)
//
#include <hip/hip_runtime.h>

static constexpr int D = 64;          // N_FACTORS
static constexpr int N_LAYERS = 3;

// ---------------------------------------------------------------------------
// k_init: emb0 = concat(user_emb, item_emb); write it to both `cur` (layer
// input) and `acc` (running sum, lives in d_out). float4 vectorized.
// ---------------------------------------------------------------------------
__global__ void k_init(const float4* __restrict__ ue, const float4* __restrict__ ie,
                       float4* __restrict__ cur, float4* __restrict__ acc,
                       int nUser4, int nTot4) {
    int stride = gridDim.x * blockDim.x;
    for (int i = blockIdx.x * blockDim.x + threadIdx.x; i < nTot4; i += stride) {
        float4 v = (i < nUser4) ? ue[i] : ie[i - nUser4];
        cur[i] = v;
        acc[i] = v;
    }
}

// ---------------------------------------------------------------------------
// k_spmm: y[row[e], :] += val[e] * x[col[e], :]   (COO scatter with atomics)
// Work item = (edge, 16B chunk): 16 lanes cover one edge's 64 floats.
// Gather is a coalesced float4 load of a 256B row segment; scatter is 4 fp32
// global atomics. Both x and y are ~38 MB -> L2/L3 resident.
// ---------------------------------------------------------------------------
__global__ void k_spmm(const int* __restrict__ row, const int* __restrict__ col,
                       const float* __restrict__ val, const float* __restrict__ x,
                       float* __restrict__ y, int nnz) {
    long long total  = (long long)nnz * 16;
    long long stride = (long long)gridDim.x * blockDim.x;
    for (long long idx = (long long)blockIdx.x * blockDim.x + threadIdx.x;
         idx < total; idx += stride) {
        int e = (int)(idx >> 4);
        int c = (int)(idx & 15);
        int r = row[e];
        int s = col[e];
        float v = val[e];
        float4 xv = *(const float4*)(x + (size_t)s * D + c * 4);
        float* yp = y + (size_t)r * D + c * 4;
        atomicAdd(yp + 0, v * xv.x);
        atomicAdd(yp + 1, v * xv.y);
        atomicAdd(yp + 2, v * xv.z);
        atomicAdd(yp + 3, v * xv.w);
    }
}

// ---------------------------------------------------------------------------
// k_acc: acc = (acc + nxt) * scale   (scale=1 for layers 0..1, 0.25 on last)
// ---------------------------------------------------------------------------
__global__ void k_acc(const float4* __restrict__ nxt, float4* __restrict__ acc,
                      float scale, int n4) {
    int stride = gridDim.x * blockDim.x;
    for (int i = blockIdx.x * blockDim.x + threadIdx.x; i < n4; i += stride) {
        float4 a = acc[i];
        float4 b = nxt[i];
        a.x = (a.x + b.x) * scale;
        a.y = (a.y + b.y) * scale;
        a.z = (a.z + b.z) * scale;
        a.w = (a.w + b.w) * scale;
        acc[i] = a;
    }
}

extern "C" void kernel_launch(void* const* d_in, const int* in_sizes, int n_in,
                              void* d_out, int out_size, void* d_ws, size_t ws_size,
                              hipStream_t stream) {
    const float* ue  = (const float*)d_in[0];
    const float* ie  = (const float*)d_in[1];
    const int*   row = (const int*)  d_in[2];
    const int*   col = (const int*)  d_in[3];
    const float* val = (const float*)d_in[4];

    const int n_users = in_sizes[0] / D;
    const int n_items = in_sizes[1] / D;
    const int nnz     = in_sizes[2];
    const int N       = n_users + n_items;

    float* acc  = (float*)d_out;               // running sum, N*D floats
    float* bufA = (float*)d_ws;                // layer ping-pong buffers
    float* bufB = bufA + (size_t)N * D;

    const int nTot4  = N * D / 4;
    const int nUser4 = n_users * D / 4;

    // init: cur = acc = emb0
    k_init<<<2048, 256, 0, stream>>>((const float4*)ue, (const float4*)ie,
                                     (float4*)bufA, (float4*)acc, nUser4, nTot4);

    float* cur = bufA;
    float* nxt = bufB;
    for (int l = 0; l < N_LAYERS; ++l) {
        hipMemsetAsync(nxt, 0, (size_t)N * D * sizeof(float), stream);
        k_spmm<<<8192, 256, 0, stream>>>(row, col, val, cur, nxt, nnz);
        float scale = (l == N_LAYERS - 1) ? (1.0f / (N_LAYERS + 1)) : 1.0f;
        k_acc<<<2048, 256, 0, stream>>>((const float4*)nxt, (float4*)acc, scale, nTot4);
        float* t = cur; cur = nxt; nxt = t;
    }
}

// Round 2
// 1133.110 us; speedup vs baseline: 10.8685x; 10.8685x over previous
//
#include <hip/hip_runtime.h>

static constexpr int D = 64;          // N_FACTORS
static constexpr int N_LAYERS = 3;

// ===========================================================================
// Common
// ===========================================================================
__global__ void k_init(const float4* __restrict__ ue, const float4* __restrict__ ie,
                       float4* __restrict__ cur, float4* __restrict__ acc,
                       int nUser4, int nTot4) {
    int stride = gridDim.x * blockDim.x;
    for (int i = blockIdx.x * blockDim.x + threadIdx.x; i < nTot4; i += stride) {
        float4 v = (i < nUser4) ? ue[i] : ie[i - nUser4];
        cur[i] = v;
        acc[i] = v;
    }
}

// ===========================================================================
// CSR build (counting sort by row) — runs every call, ws is re-poisoned
// ===========================================================================
__global__ void k_hist(const int* __restrict__ row, int* __restrict__ counts, int nnz) {
    int stride = gridDim.x * blockDim.x;
    for (int e = blockIdx.x * blockDim.x + threadIdx.x; e < nnz; e += stride)
        atomicAdd(&counts[row[e]], 1);
}

// Per-block exclusive scan of 1024 elements (256 thr x 4), emits block sums.
__global__ void k_scan_block(const int* __restrict__ counts, int* __restrict__ out,
                             int* __restrict__ bsums, int n) {
    __shared__ int s[256];
    int base = blockIdx.x * 1024 + threadIdx.x * 4;
    int c0 = (base + 0 < n) ? counts[base + 0] : 0;
    int c1 = (base + 1 < n) ? counts[base + 1] : 0;
    int c2 = (base + 2 < n) ? counts[base + 2] : 0;
    int c3 = (base + 3 < n) ? counts[base + 3] : 0;
    int tsum = c0 + c1 + c2 + c3;
    s[threadIdx.x] = tsum;
    __syncthreads();
    for (int off = 1; off < 256; off <<= 1) {
        int v = (threadIdx.x >= off) ? s[threadIdx.x - off] : 0;
        __syncthreads();
        s[threadIdx.x] += v;
        __syncthreads();
    }
    int excl = s[threadIdx.x] - tsum;
    if (threadIdx.x == 255) bsums[blockIdx.x] = s[255];
    if (base + 0 < n) out[base + 0] = excl;
    if (base + 1 < n) out[base + 1] = excl + c0;
    if (base + 2 < n) out[base + 2] = excl + c0 + c1;
    if (base + 3 < n) out[base + 3] = excl + c0 + c1 + c2;
}

// Single-block exclusive scan of the block sums (nB <= 256 for N=150k).
__global__ void k_scan_sums(int* __restrict__ bsums, int nB) {
    __shared__ int s[256];
    int v = (threadIdx.x < nB) ? bsums[threadIdx.x] : 0;
    s[threadIdx.x] = v;
    __syncthreads();
    for (int off = 1; off < 256; off <<= 1) {
        int u = (threadIdx.x >= off) ? s[threadIdx.x - off] : 0;
        __syncthreads();
        s[threadIdx.x] += u;
        __syncthreads();
    }
    if (threadIdx.x < nB) bsums[threadIdx.x] = s[threadIdx.x] - v;
}

// rowptr[i] += scanned block sum; cursor = rowptr; rowptr[N] = nnz.
__global__ void k_finalize(int* __restrict__ rowptr, int* __restrict__ cursor,
                           const int* __restrict__ bsums, int n, int nnz) {
    int stride = gridDim.x * blockDim.x;
    for (int i = blockIdx.x * blockDim.x + threadIdx.x; i <= n; i += stride) {
        if (i < n) {
            int v = rowptr[i] + bsums[i >> 10];
            rowptr[i] = v;
            cursor[i] = v;
        } else {
            rowptr[n] = nnz;
        }
    }
}

// Bucket edges by row: ecv[p] = (col, val-bits)
__global__ void k_scatter(const int* __restrict__ row, const int* __restrict__ col,
                          const float* __restrict__ val, int* __restrict__ cursor,
                          int2* __restrict__ ecv, int nnz) {
    int stride = gridDim.x * blockDim.x;
    for (int e = blockIdx.x * blockDim.x + threadIdx.x; e < nnz; e += stride) {
        int r = row[e];
        int p = atomicAdd(&cursor[r], 1);
        ecv[p] = make_int2(col[e], __float_as_int(val[e]));
    }
}

// ===========================================================================
// Gather SpMM: one wave per row, lane l owns output element l (D == 64).
// Fused running-mean update: acc += y (and *0.25 on last layer).
// ===========================================================================
template <bool WRITE_Y, bool LAST>
__global__ void k_spmm_csr(const int* __restrict__ rowptr, const int2* __restrict__ ecv,
                           const float* __restrict__ x, float* __restrict__ y,
                           float* __restrict__ acc, int N) {
    int r    = (blockIdx.x * blockDim.x + threadIdx.x) >> 6;
    int lane = threadIdx.x & 63;
    if (r >= N) return;
    int e  = rowptr[r];
    int e1 = rowptr[r + 1];
    float s0 = 0.f, s1 = 0.f, s2 = 0.f, s3 = 0.f;
    for (; e + 3 < e1; e += 4) {
        int2 a = ecv[e + 0];
        int2 b = ecv[e + 1];
        int2 c = ecv[e + 2];
        int2 d = ecv[e + 3];
        s0 += __int_as_float(a.y) * x[(size_t)a.x * D + lane];
        s1 += __int_as_float(b.y) * x[(size_t)b.x * D + lane];
        s2 += __int_as_float(c.y) * x[(size_t)c.x * D + lane];
        s3 += __int_as_float(d.y) * x[(size_t)d.x * D + lane];
    }
    for (; e < e1; ++e) {
        int2 a = ecv[e];
        s0 += __int_as_float(a.y) * x[(size_t)a.x * D + lane];
    }
    float sum = (s0 + s1) + (s2 + s3);
    size_t o = (size_t)r * D + lane;
    if (WRITE_Y) y[o] = sum;
    float av = acc[o] + sum;
    acc[o] = LAST ? av * (1.0f / (N_LAYERS + 1)) : av;
}

// ===========================================================================
// Fallback (round-1 atomic path) if ws is too small for CSR
// ===========================================================================
__global__ void k_spmm_atomic(const int* __restrict__ row, const int* __restrict__ col,
                              const float* __restrict__ val, const float* __restrict__ x,
                              float* __restrict__ y, int nnz) {
    long long total  = (long long)nnz * 16;
    long long stride = (long long)gridDim.x * blockDim.x;
    for (long long idx = (long long)blockIdx.x * blockDim.x + threadIdx.x;
         idx < total; idx += stride) {
        int e = (int)(idx >> 4);
        int c = (int)(idx & 15);
        int r = row[e];
        int s = col[e];
        float v = val[e];
        float4 xv = *(const float4*)(x + (size_t)s * D + c * 4);
        float* yp = y + (size_t)r * D + c * 4;
        atomicAdd(yp + 0, v * xv.x);
        atomicAdd(yp + 1, v * xv.y);
        atomicAdd(yp + 2, v * xv.z);
        atomicAdd(yp + 3, v * xv.w);
    }
}

__global__ void k_acc(const float4* __restrict__ nxt, float4* __restrict__ acc,
                      float scale, int n4) {
    int stride = gridDim.x * blockDim.x;
    for (int i = blockIdx.x * blockDim.x + threadIdx.x; i < n4; i += stride) {
        float4 a = acc[i];
        float4 b = nxt[i];
        a.x = (a.x + b.x) * scale;
        a.y = (a.y + b.y) * scale;
        a.z = (a.z + b.z) * scale;
        a.w = (a.w + b.w) * scale;
        acc[i] = a;
    }
}

// ===========================================================================
extern "C" void kernel_launch(void* const* d_in, const int* in_sizes, int n_in,
                              void* d_out, int out_size, void* d_ws, size_t ws_size,
                              hipStream_t stream) {
    const float* ue  = (const float*)d_in[0];
    const float* ie  = (const float*)d_in[1];
    const int*   row = (const int*)  d_in[2];
    const int*   col = (const int*)  d_in[3];
    const float* val = (const float*)d_in[4];

    const int n_users = in_sizes[0] / D;
    const int n_items = in_sizes[1] / D;
    const int nnz     = in_sizes[2];
    const int N       = n_users + n_items;

    float* acc = (float*)d_out;

    const size_t denseB = (size_t)N * D * sizeof(float);   // 38.4 MB
    const size_t align  = 256;
    auto aup = [&](size_t x) { return (x + align - 1) & ~(align - 1); };

    // CSR-path workspace layout
    size_t off = 0;
    float* bufA   = (float*)((char*)d_ws + off); off += aup(denseB);
    float* bufB   = (float*)((char*)d_ws + off); off += aup(denseB);
    int2*  ecv    = (int2*) ((char*)d_ws + off); off += aup((size_t)nnz * 8);
    int*   rowptr = (int*)  ((char*)d_ws + off); off += aup((size_t)(N + 1) * 4);
    int*   cursor = (int*)  ((char*)d_ws + off); off += aup((size_t)N * 4);
    int*   bsums  = (int*)  ((char*)d_ws + off); off += aup(1024 * 4);
    const size_t needCSR = off;

    const int nTot4  = N * D / 4;
    const int nUser4 = n_users * D / 4;

    if (ws_size >= needCSR) {
        // ---- build CSR (counting sort by row) ----
        hipMemsetAsync(cursor, 0, (size_t)N * 4, stream);        // counts
        k_hist<<<(nnz + 255) / 256, 256, 0, stream>>>(row, cursor, nnz);
        int nB = (N + 1023) / 1024;                               // 147 <= 256
        k_scan_block<<<nB, 256, 0, stream>>>(cursor, rowptr, bsums, N);
        k_scan_sums<<<1, 256, 0, stream>>>(bsums, nB);
        k_finalize<<<(N + 256) / 256, 256, 0, stream>>>(rowptr, cursor, bsums, N, nnz);
        k_scatter<<<(nnz + 255) / 256, 256, 0, stream>>>(row, col, val, cursor, ecv, nnz);

        // ---- init + 3 fused SpMM layers ----
        k_init<<<2048, 256, 0, stream>>>((const float4*)ue, (const float4*)ie,
                                         (float4*)bufA, (float4*)acc, nUser4, nTot4);
        int grid = (N * 64 + 255) / 256;   // one wave per row, 4 rows/block
        k_spmm_csr<true,  false><<<grid, 256, 0, stream>>>(rowptr, ecv, bufA, bufB, acc, N);
        k_spmm_csr<true,  false><<<grid, 256, 0, stream>>>(rowptr, ecv, bufB, bufA, acc, N);
        k_spmm_csr<false, true ><<<grid, 256, 0, stream>>>(rowptr, ecv, bufA, bufA, acc, N);
    } else {
        // ---- fallback: atomic scatter path (round-1) ----
        float* fa = (float*)d_ws;
        float* fb = fa + (size_t)N * D;
        k_init<<<2048, 256, 0, stream>>>((const float4*)ue, (const float4*)ie,
                                         (float4*)fa, (float4*)acc, nUser4, nTot4);
        float* cur = fa;
        float* nxt = fb;
        for (int l = 0; l < N_LAYERS; ++l) {
            hipMemsetAsync(nxt, 0, denseB, stream);
            k_spmm_atomic<<<8192, 256, 0, stream>>>(row, col, val, cur, nxt, nnz);
            float scale = (l == N_LAYERS - 1) ? (1.0f / (N_LAYERS + 1)) : 1.0f;
            k_acc<<<2048, 256, 0, stream>>>((const float4*)nxt, (float4*)acc, scale, nTot4);
            float* t = cur; cur = nxt; nxt = t;
        }
    }
}